// Round 1
// baseline (109.040 us; speedup 1.0000x reference)
//
#include <hip/hip_runtime.h>

// Chamfer distance, fp32 VALU, register-tiled, packed-fp32 math.
// dist(p,q) = |p|^2 + |q|^2 - 2 p.q ; |p|^2 folded out of the min, |q|^2
// precomputed during LDS staging.
//
// R3 post-mortem: broadcast ds_read_b128 is issue-bound (~4cyc, not 12) ->
// LDS pipe fine; true VALU = 47% of runtime (reported 95% = gfx94x formula
// x2); rest is latency at 2 waves/SIMD.
// R4: v_pk_fma_f32 packed pairs + 512-thread blocks -> 48.5us dispatch.
// R5 theory: true VALU issue ~30% (13.7us floor vs 48.5us) and
// OccupancyPercent ~30 -> latency-bound at 2 blocks/CU (grid=512 is the
// cap, not LDS/VGPR). Split the target dim 2x: each block scans 4096
// targets -> 1024 blocks = 4 blocks/CU = 32 waves/CU (HW cap). Per-point
// full mins (|p|^2 added back; bit-identical by monotone rounding) go to
// d_ws [point][split] race-free; a tiny second kernel mins the 2 splits
// and sums in double. Predict: occupancy ~2x, dispatch 48.5 -> ~30us.

#define THREADS 512
#define P 8        // src points per thread (4 packed pairs)
#define S 32       // target slices per block (one 16-lane group per slice)
#define G 128      // src points per block = 16 lanes * P
#define TILE 64    // targets per slice per staging tile
#define LSTRIDE (TILE + 1)  // +1 float4 pad -> disjoint banks across groups
#define TSPLIT 2   // target-dimension split across blocks (occupancy)

typedef float float2_t __attribute__((ext_vector_type(2)));
typedef float float4_t __attribute__((ext_vector_type(4)));

// d = a * bcast_lo(b) + bcast_hi(b)   (b = {qz,qw}: d = a*qz + qw)
static __device__ __forceinline__ float2_t pk_fma_bl_bh(float2_t a, float2_t b) {
  float2_t d;
  asm("v_pk_fma_f32 %0, %1, %2, %2 op_sel:[0,0,1] op_sel_hi:[1,0,1]"
      : "=v"(d) : "v"(a), "v"(b));
  return d;
}
// d = a * bcast_hi(b) + c
static __device__ __forceinline__ float2_t pk_fma_bh(float2_t a, float2_t b, float2_t c) {
  float2_t d;
  asm("v_pk_fma_f32 %0, %1, %2, %3 op_sel:[0,1,0] op_sel_hi:[1,1,1]"
      : "=v"(d) : "v"(a), "v"(b), "v"(c));
  return d;
}
// d = a * bcast_lo(b) + c
static __device__ __forceinline__ float2_t pk_fma_bl(float2_t a, float2_t b, float2_t c) {
  float2_t d;
  asm("v_pk_fma_f32 %0, %1, %2, %3 op_sel:[0,0,0] op_sel_hi:[1,0,1]"
      : "=v"(d) : "v"(a), "v"(b), "v"(c));
  return d;
}

__global__ __launch_bounds__(THREADS, 8) void chamfer_min_kernel(
    const float* __restrict__ pred, const float* __restrict__ target,
    float* __restrict__ wsmin, int M) {
  const int blocksPerDir = M / G;  // 64
  int bid = blockIdx.x;
  int pblk = bid % blocksPerDir;
  int rest = bid / blocksPerDir;
  int ts = rest % TSPLIT;          // which target half
  int bd = rest / TSPLIT;
  int dir = bd & 1;
  int b = bd >> 1;
  const float* src = (dir ? target : pred) + (size_t)b * M * 3;
  const float* ref = (dir ? pred : target) + (size_t)b * M * 3;

  __shared__ float4_t lds[S * LSTRIDE];  // 33.3 KB; reused in epilogue

  int t = threadIdx.x;
  int g = t >> 4;  // slice 0..31 (uniform per 16-lane group)
  int l = t & 15;

  float cm[P];
  float2_t a2x[P / 2], a2y[P / 2], a2z[P / 2];
  int pbase = pblk * G;
#pragma unroll
  for (int i = 0; i < P / 2; ++i) {
    int p0 = pbase + l + 16 * (2 * i);
    int p1 = pbase + l + 16 * (2 * i + 1);
    float x0 = src[p0 * 3 + 0], y0 = src[p0 * 3 + 1], z0 = src[p0 * 3 + 2];
    float x1 = src[p1 * 3 + 0], y1 = src[p1 * 3 + 1], z1 = src[p1 * 3 + 2];
    cm[2 * i] = x0 * x0 + y0 * y0 + z0 * z0;
    cm[2 * i + 1] = x1 * x1 + y1 * y1 + z1 * z1;
    a2x[i] = (float2_t){-2.f * x0, -2.f * x1};
    a2y[i] = (float2_t){-2.f * y0, -2.f * y1};
    a2z[i] = (float2_t){-2.f * z0, -2.f * z1};
  }
  float mlo[P / 2], mhi[P / 2];
#pragma unroll
  for (int i = 0; i < P / 2; ++i) { mlo[i] = 3.0e38f; mhi[i] = 3.0e38f; }

  const int spanLen = M / TSPLIT;      // 4096 targets for this block
  const int tbase = ts * spanLen;
  const int sliceLen = spanLen / S;    // 128
  const int ntiles = sliceLen / TILE;  // 2
  for (int k = 0; k < ntiles; ++k) {
    __syncthreads();  // previous tile's readers done before overwrite
#pragma unroll
    for (int i = 0; i < (S * TILE) / THREADS; ++i) {  // 4 entries/thread
      int idx = t + THREADS * i;
      int s = idx >> 6;         // idx / TILE
      int jj = idx & (TILE - 1);
      int n = tbase + s * sliceLen + k * TILE + jj;
      float qx = ref[n * 3 + 0], qy = ref[n * 3 + 1], qz = ref[n * 3 + 2];
      lds[s * LSTRIDE + jj] =
          (float4_t){qx, qy, qz, qx * qx + qy * qy + qz * qz};
    }
    __syncthreads();
    const float4_t* tp = lds + g * LSTRIDE;  // uniform per 16-lane group
#pragma unroll 2
    for (int j = 0; j < TILE; j += 4) {
      float4_t q0 = tp[j + 0];  // broadcast reads, disjoint banks per wave
      float4_t q1 = tp[j + 1];
      float4_t q2 = tp[j + 2];
      float4_t q3 = tp[j + 3];
      float2_t q0xy = __builtin_shufflevector(q0, q0, 0, 1);
      float2_t q0zw = __builtin_shufflevector(q0, q0, 2, 3);
      float2_t q1xy = __builtin_shufflevector(q1, q1, 0, 1);
      float2_t q1zw = __builtin_shufflevector(q1, q1, 2, 3);
      float2_t q2xy = __builtin_shufflevector(q2, q2, 0, 1);
      float2_t q2zw = __builtin_shufflevector(q2, q2, 2, 3);
      float2_t q3xy = __builtin_shufflevector(q3, q3, 0, 1);
      float2_t q3zw = __builtin_shufflevector(q3, q3, 2, 3);
#pragma unroll
      for (int i = 0; i < P / 2; ++i) {
        // d = ax*qx + ay*qy + az*qz + qw, two points per packed chain
        float2_t d0 = pk_fma_bl(a2x[i], q0xy,
                        pk_fma_bh(a2y[i], q0xy, pk_fma_bl_bh(a2z[i], q0zw)));
        float2_t d1 = pk_fma_bl(a2x[i], q1xy,
                        pk_fma_bh(a2y[i], q1xy, pk_fma_bl_bh(a2z[i], q1zw)));
        float2_t d2 = pk_fma_bl(a2x[i], q2xy,
                        pk_fma_bh(a2y[i], q2xy, pk_fma_bl_bh(a2z[i], q2zw)));
        float2_t d3 = pk_fma_bl(a2x[i], q3xy,
                        pk_fma_bh(a2y[i], q3xy, pk_fma_bl_bh(a2z[i], q3zw)));
        mlo[i] = fminf(fminf(mlo[i], d0.x), d1.x);  // v_min3
        mlo[i] = fminf(fminf(mlo[i], d2.x), d3.x);
        mhi[i] = fminf(fminf(mhi[i], d0.y), d1.y);
        mhi[i] = fminf(fminf(mhi[i], d2.y), d3.y);
      }
    }
  }

  // Combine the S slice-mins per point, add |p|^2 back, store per-split min.
  __syncthreads();
  float* lmin = (float*)lds;          // [S][G] floats (16 KB, overlays staging)
  float* lcm = (float*)lds + S * G;   // [G] floats
#pragma unroll
  for (int i = 0; i < P / 2; ++i) {
    lmin[g * G + (l + 16 * (2 * i))] = mlo[i];
    lmin[g * G + (l + 16 * (2 * i + 1))] = mhi[i];
    if (g == 0) {
      lcm[l + 16 * (2 * i)] = cm[2 * i];
      lcm[l + 16 * (2 * i + 1)] = cm[2 * i + 1];
    }
  }
  __syncthreads();
  if (t < G) {
    float mn = 3.0e38f;
#pragma unroll
    for (int s = 0; s < S; ++s) mn = fminf(mn, lmin[s * G + t]);
    int pid = (b * 2 + dir) * M + pbase + t;       // global point id
    wsmin[(size_t)pid * TSPLIT + ts] = lcm[t] + mn;
  }
}

// Min over the TSPLIT partials per point, then sum everything (double acc).
__global__ __launch_bounds__(256) void chamfer_reduce_kernel(
    const float* __restrict__ wsmin, float* __restrict__ out, int npts,
    float scale) {
  int tid = blockIdx.x * blockDim.x + threadIdx.x;
  int stride = gridDim.x * blockDim.x;
  double acc = 0.0;
  for (int p = tid; p < npts; p += stride) {
    float2_t v = ((const float2_t*)wsmin)[p];  // TSPLIT=2 contiguous
    acc += (double)fminf(v.x, v.y);
  }
  for (int off = 32; off > 0; off >>= 1) acc += __shfl_down(acc, off, 64);
  __shared__ double wsum[256 / 64];
  int t = threadIdx.x;
  if ((t & 63) == 0) wsum[t >> 6] = acc;
  __syncthreads();
  if (t == 0) {
    double s = 0.0;
#pragma unroll
    for (int w = 0; w < 256 / 64; ++w) s += wsum[w];
    atomicAdd(out, (float)(s * (double)scale));
  }
}

extern "C" void kernel_launch(void* const* d_in, const int* in_sizes, int n_in,
                              void* d_out, int out_size, void* d_ws,
                              size_t ws_size, hipStream_t stream) {
  const float* pred = (const float*)d_in[0];
  const float* target = (const float*)d_in[1];
  float* out = (float*)d_out;
  float* wsmin = (float*)d_ws;  // B*2*M*TSPLIT floats = 512 KB
  const int B = 4;
  const int M = in_sizes[0] / (B * 3);  // 8192

  // mean_b[ mean_m(min) + mean_n(min) ] with M==N  ->  sum_all / (B*M)
  float scale = 1.0f / (float)(B * M);

  hipMemsetAsync(out, 0, sizeof(float), stream);  // d_out is poisoned 0xAA
  int blocks = B * 2 * (M / G) * TSPLIT;          // 1024
  chamfer_min_kernel<<<blocks, THREADS, 0, stream>>>(pred, target, wsmin, M);
  int npts = B * 2 * M;                           // 65536
  chamfer_reduce_kernel<<<64, 256, 0, stream>>>(wsmin, out, npts, scale);
}

// Round 2
// 97.673 us; speedup vs baseline: 1.1164x; 1.1164x over previous
//
#include <hip/hip_runtime.h>

// Chamfer distance, fp32 VALU, register-tiled, packed-fp32 math.
// dist(p,q) = |p|^2 + |q|^2 - 2 p.q ; |p|^2 folded out of the min, |q|^2
// precomputed during LDS staging.
//
// R4: v_pk_fma_f32 packed pairs + 512-thread blocks -> 48.5us dispatch.
// R5: TSPLIT=2 target split -> 1024 blocks (4/CU). Occupancy 30->55% as
// predicted BUT __launch_bounds__(512,8) forced a 64-VGPR cap -> allocator
// collapsed 52->32 VGPRs with scratch spills of the a2*/cm point state:
// WRITE_SIZE 16KB->55.8MB, FETCH 3.1->31.8MB, dispatch 48.5->53.5us.
// R6: bound relaxed to (512,4). LDS (33.3KB) already limits to 4 blocks/CU
// = 32 waves/CU = HW cap, and 52 VGPR allows 9 waves/SIMD -- the (,,8)
// bound was unnecessary for the occupancy it was buying. Predict: VGPR ~52,
// WRITE back to ~0.55MB, dispatch ~28-34us.

#define THREADS 512
#define P 8        // src points per thread (4 packed pairs)
#define S 32       // target slices per block (one 16-lane group per slice)
#define G 128      // src points per block = 16 lanes * P
#define TILE 64    // targets per slice per staging tile
#define LSTRIDE (TILE + 1)  // +1 float4 pad -> disjoint banks across groups
#define TSPLIT 2   // target-dimension split across blocks (occupancy)

typedef float float2_t __attribute__((ext_vector_type(2)));
typedef float float4_t __attribute__((ext_vector_type(4)));

// d = a * bcast_lo(b) + bcast_hi(b)   (b = {qz,qw}: d = a*qz + qw)
static __device__ __forceinline__ float2_t pk_fma_bl_bh(float2_t a, float2_t b) {
  float2_t d;
  asm("v_pk_fma_f32 %0, %1, %2, %2 op_sel:[0,0,1] op_sel_hi:[1,0,1]"
      : "=v"(d) : "v"(a), "v"(b));
  return d;
}
// d = a * bcast_hi(b) + c
static __device__ __forceinline__ float2_t pk_fma_bh(float2_t a, float2_t b, float2_t c) {
  float2_t d;
  asm("v_pk_fma_f32 %0, %1, %2, %3 op_sel:[0,1,0] op_sel_hi:[1,1,1]"
      : "=v"(d) : "v"(a), "v"(b), "v"(c));
  return d;
}
// d = a * bcast_lo(b) + c
static __device__ __forceinline__ float2_t pk_fma_bl(float2_t a, float2_t b, float2_t c) {
  float2_t d;
  asm("v_pk_fma_f32 %0, %1, %2, %3 op_sel:[0,0,0] op_sel_hi:[1,0,1]"
      : "=v"(d) : "v"(a), "v"(b), "v"(c));
  return d;
}

__global__ __launch_bounds__(THREADS, 4) void chamfer_min_kernel(
    const float* __restrict__ pred, const float* __restrict__ target,
    float* __restrict__ wsmin, int M) {
  const int blocksPerDir = M / G;  // 64
  int bid = blockIdx.x;
  int pblk = bid % blocksPerDir;
  int rest = bid / blocksPerDir;
  int ts = rest % TSPLIT;          // which target half
  int bd = rest / TSPLIT;
  int dir = bd & 1;
  int b = bd >> 1;
  const float* src = (dir ? target : pred) + (size_t)b * M * 3;
  const float* ref = (dir ? pred : target) + (size_t)b * M * 3;

  __shared__ float4_t lds[S * LSTRIDE];  // 33.3 KB; reused in epilogue

  int t = threadIdx.x;
  int g = t >> 4;  // slice 0..31 (uniform per 16-lane group)
  int l = t & 15;

  float cm[P];
  float2_t a2x[P / 2], a2y[P / 2], a2z[P / 2];
  int pbase = pblk * G;
#pragma unroll
  for (int i = 0; i < P / 2; ++i) {
    int p0 = pbase + l + 16 * (2 * i);
    int p1 = pbase + l + 16 * (2 * i + 1);
    float x0 = src[p0 * 3 + 0], y0 = src[p0 * 3 + 1], z0 = src[p0 * 3 + 2];
    float x1 = src[p1 * 3 + 0], y1 = src[p1 * 3 + 1], z1 = src[p1 * 3 + 2];
    cm[2 * i] = x0 * x0 + y0 * y0 + z0 * z0;
    cm[2 * i + 1] = x1 * x1 + y1 * y1 + z1 * z1;
    a2x[i] = (float2_t){-2.f * x0, -2.f * x1};
    a2y[i] = (float2_t){-2.f * y0, -2.f * y1};
    a2z[i] = (float2_t){-2.f * z0, -2.f * z1};
  }
  float mlo[P / 2], mhi[P / 2];
#pragma unroll
  for (int i = 0; i < P / 2; ++i) { mlo[i] = 3.0e38f; mhi[i] = 3.0e38f; }

  const int spanLen = M / TSPLIT;      // 4096 targets for this block
  const int tbase = ts * spanLen;
  const int sliceLen = spanLen / S;    // 128
  const int ntiles = sliceLen / TILE;  // 2
  for (int k = 0; k < ntiles; ++k) {
    __syncthreads();  // previous tile's readers done before overwrite
#pragma unroll
    for (int i = 0; i < (S * TILE) / THREADS; ++i) {  // 4 entries/thread
      int idx = t + THREADS * i;
      int s = idx >> 6;         // idx / TILE
      int jj = idx & (TILE - 1);
      int n = tbase + s * sliceLen + k * TILE + jj;
      float qx = ref[n * 3 + 0], qy = ref[n * 3 + 1], qz = ref[n * 3 + 2];
      lds[s * LSTRIDE + jj] =
          (float4_t){qx, qy, qz, qx * qx + qy * qy + qz * qz};
    }
    __syncthreads();
    const float4_t* tp = lds + g * LSTRIDE;  // uniform per 16-lane group
#pragma unroll 2
    for (int j = 0; j < TILE; j += 4) {
      float4_t q0 = tp[j + 0];  // broadcast reads, disjoint banks per wave
      float4_t q1 = tp[j + 1];
      float4_t q2 = tp[j + 2];
      float4_t q3 = tp[j + 3];
      float2_t q0xy = __builtin_shufflevector(q0, q0, 0, 1);
      float2_t q0zw = __builtin_shufflevector(q0, q0, 2, 3);
      float2_t q1xy = __builtin_shufflevector(q1, q1, 0, 1);
      float2_t q1zw = __builtin_shufflevector(q1, q1, 2, 3);
      float2_t q2xy = __builtin_shufflevector(q2, q2, 0, 1);
      float2_t q2zw = __builtin_shufflevector(q2, q2, 2, 3);
      float2_t q3xy = __builtin_shufflevector(q3, q3, 0, 1);
      float2_t q3zw = __builtin_shufflevector(q3, q3, 2, 3);
#pragma unroll
      for (int i = 0; i < P / 2; ++i) {
        // d = ax*qx + ay*qy + az*qz + qw, two points per packed chain
        float2_t d0 = pk_fma_bl(a2x[i], q0xy,
                        pk_fma_bh(a2y[i], q0xy, pk_fma_bl_bh(a2z[i], q0zw)));
        float2_t d1 = pk_fma_bl(a2x[i], q1xy,
                        pk_fma_bh(a2y[i], q1xy, pk_fma_bl_bh(a2z[i], q1zw)));
        float2_t d2 = pk_fma_bl(a2x[i], q2xy,
                        pk_fma_bh(a2y[i], q2xy, pk_fma_bl_bh(a2z[i], q2zw)));
        float2_t d3 = pk_fma_bl(a2x[i], q3xy,
                        pk_fma_bh(a2y[i], q3xy, pk_fma_bl_bh(a2z[i], q3zw)));
        mlo[i] = fminf(fminf(mlo[i], d0.x), d1.x);  // v_min3
        mlo[i] = fminf(fminf(mlo[i], d2.x), d3.x);
        mhi[i] = fminf(fminf(mhi[i], d0.y), d1.y);
        mhi[i] = fminf(fminf(mhi[i], d2.y), d3.y);
      }
    }
  }

  // Combine the S slice-mins per point, add |p|^2 back, store per-split min.
  __syncthreads();
  float* lmin = (float*)lds;          // [S][G] floats (16 KB, overlays staging)
  float* lcm = (float*)lds + S * G;   // [G] floats
#pragma unroll
  for (int i = 0; i < P / 2; ++i) {
    lmin[g * G + (l + 16 * (2 * i))] = mlo[i];
    lmin[g * G + (l + 16 * (2 * i + 1))] = mhi[i];
    if (g == 0) {
      lcm[l + 16 * (2 * i)] = cm[2 * i];
      lcm[l + 16 * (2 * i + 1)] = cm[2 * i + 1];
    }
  }
  __syncthreads();
  if (t < G) {
    float mn = 3.0e38f;
#pragma unroll
    for (int s = 0; s < S; ++s) mn = fminf(mn, lmin[s * G + t]);
    int pid = (b * 2 + dir) * M + pbase + t;       // global point id
    wsmin[(size_t)pid * TSPLIT + ts] = lcm[t] + mn;
  }
}

// Min over the TSPLIT partials per point, then sum everything (double acc).
__global__ __launch_bounds__(256) void chamfer_reduce_kernel(
    const float* __restrict__ wsmin, float* __restrict__ out, int npts,
    float scale) {
  int tid = blockIdx.x * blockDim.x + threadIdx.x;
  int stride = gridDim.x * blockDim.x;
  double acc = 0.0;
  for (int p = tid; p < npts; p += stride) {
    float2_t v = ((const float2_t*)wsmin)[p];  // TSPLIT=2 contiguous
    acc += (double)fminf(v.x, v.y);
  }
  for (int off = 32; off > 0; off >>= 1) acc += __shfl_down(acc, off, 64);
  __shared__ double wsum[256 / 64];
  int t = threadIdx.x;
  if ((t & 63) == 0) wsum[t >> 6] = acc;
  __syncthreads();
  if (t == 0) {
    double s = 0.0;
#pragma unroll
    for (int w = 0; w < 256 / 64; ++w) s += wsum[w];
    atomicAdd(out, (float)(s * (double)scale));
  }
}

extern "C" void kernel_launch(void* const* d_in, const int* in_sizes, int n_in,
                              void* d_out, int out_size, void* d_ws,
                              size_t ws_size, hipStream_t stream) {
  const float* pred = (const float*)d_in[0];
  const float* target = (const float*)d_in[1];
  float* out = (float*)d_out;
  float* wsmin = (float*)d_ws;  // B*2*M*TSPLIT floats = 512 KB
  const int B = 4;
  const int M = in_sizes[0] / (B * 3);  // 8192

  // mean_b[ mean_m(min) + mean_n(min) ] with M==N  ->  sum_all / (B*M)
  float scale = 1.0f / (float)(B * M);

  hipMemsetAsync(out, 0, sizeof(float), stream);  // d_out is poisoned 0xAA
  int blocks = B * 2 * (M / G) * TSPLIT;          // 1024
  chamfer_min_kernel<<<blocks, THREADS, 0, stream>>>(pred, target, wsmin, M);
  int npts = B * 2 * M;                           // 65536
  chamfer_reduce_kernel<<<64, 256, 0, stream>>>(wsmin, out, npts, scale);
}

// Round 3
// 97.113 us; speedup vs baseline: 1.1228x; 1.0058x over previous
//
#include <hip/hip_runtime.h>

// Chamfer distance, fp32 VALU, register-tiled, packed-fp32 math.
// dist(p,q) = |p|^2 + |q|^2 - 2 p.q ; |p|^2 folded out of the min, |q|^2
// precomputed during LDS staging.
//
// R4: v_pk_fma_f32 packed pairs + 512-thread blocks -> 48.5us dispatch.
// R5: TSPLIT=2 (1024 blocks). launch_bounds(512,8) caused 52->32 VGPR
// spill collapse (WRITE 16KB->55.8MB), 53.5us.
// R6: bounds (512,4): spill gone (WRITE 512B) but dur 50us and occupancy
// back at 33% -- extra blocks/CU bought nothing. TLP is not the lever.
// R7 theory: v_pk_fma_f32 = 4 cyc/wave (fp32 peak is 157TF packed or not)
// -> true VALU floor ~24us; at 50us we run ~48% duty. The stall is the
// per-j-step lgkmcnt: 4 ds_read_b128 then wait ~120cy before 224cy of
// compute. Fix: software-pipeline q (prefetch next 4 float4 into regs
// during current compute). Pay the +16 VGPR by dropping cm[8] (|p|^2
// recomputed in epilogue from src, bit-identical). Predict: VALUBusy
// 62->85+, dispatch 50 -> 30-36us.

#define THREADS 512
#define P 8        // src points per thread (4 packed pairs)
#define S 32       // target slices per block (one 16-lane group per slice)
#define G 128      // src points per block = 16 lanes * P
#define TILE 64    // targets per slice per staging tile
#define LSTRIDE (TILE + 1)  // +1 float4 pad -> disjoint banks across groups
#define TSPLIT 2   // target-dimension split across blocks

typedef float float2_t __attribute__((ext_vector_type(2)));
typedef float float4_t __attribute__((ext_vector_type(4)));

// d = a * bcast_lo(b) + bcast_hi(b)   (b = {qz,qw}: d = a*qz + qw)
static __device__ __forceinline__ float2_t pk_fma_bl_bh(float2_t a, float2_t b) {
  float2_t d;
  asm("v_pk_fma_f32 %0, %1, %2, %2 op_sel:[0,0,1] op_sel_hi:[1,0,1]"
      : "=v"(d) : "v"(a), "v"(b));
  return d;
}
// d = a * bcast_hi(b) + c
static __device__ __forceinline__ float2_t pk_fma_bh(float2_t a, float2_t b, float2_t c) {
  float2_t d;
  asm("v_pk_fma_f32 %0, %1, %2, %3 op_sel:[0,1,0] op_sel_hi:[1,1,1]"
      : "=v"(d) : "v"(a), "v"(b), "v"(c));
  return d;
}
// d = a * bcast_lo(b) + c
static __device__ __forceinline__ float2_t pk_fma_bl(float2_t a, float2_t b, float2_t c) {
  float2_t d;
  asm("v_pk_fma_f32 %0, %1, %2, %3 op_sel:[0,0,0] op_sel_hi:[1,0,1]"
      : "=v"(d) : "v"(a), "v"(b), "v"(c));
  return d;
}

__global__ __launch_bounds__(THREADS, 4) void chamfer_min_kernel(
    const float* __restrict__ pred, const float* __restrict__ target,
    float* __restrict__ wsmin, int M) {
  const int blocksPerDir = M / G;  // 64
  int bid = blockIdx.x;
  int pblk = bid % blocksPerDir;
  int rest = bid / blocksPerDir;
  int ts = rest % TSPLIT;          // which target half
  int bd = rest / TSPLIT;
  int dir = bd & 1;
  int b = bd >> 1;
  const float* src = (dir ? target : pred) + (size_t)b * M * 3;
  const float* ref = (dir ? pred : target) + (size_t)b * M * 3;

  __shared__ float4_t lds[S * LSTRIDE];  // 33.3 KB; reused in epilogue

  int t = threadIdx.x;
  int g = t >> 4;  // slice 0..31 (uniform per 16-lane group)
  int l = t & 15;

  float2_t a2x[P / 2], a2y[P / 2], a2z[P / 2];
  int pbase = pblk * G;
#pragma unroll
  for (int i = 0; i < P / 2; ++i) {
    int p0 = pbase + l + 16 * (2 * i);
    int p1 = pbase + l + 16 * (2 * i + 1);
    float x0 = src[p0 * 3 + 0], y0 = src[p0 * 3 + 1], z0 = src[p0 * 3 + 2];
    float x1 = src[p1 * 3 + 0], y1 = src[p1 * 3 + 1], z1 = src[p1 * 3 + 2];
    a2x[i] = (float2_t){-2.f * x0, -2.f * x1};
    a2y[i] = (float2_t){-2.f * y0, -2.f * y1};
    a2z[i] = (float2_t){-2.f * z0, -2.f * z1};
  }
  float mlo[P / 2], mhi[P / 2];
#pragma unroll
  for (int i = 0; i < P / 2; ++i) { mlo[i] = 3.0e38f; mhi[i] = 3.0e38f; }

  const int spanLen = M / TSPLIT;      // 4096 targets for this block
  const int tbase = ts * spanLen;
  const int sliceLen = spanLen / S;    // 128
  const int ntiles = sliceLen / TILE;  // 2
  for (int k = 0; k < ntiles; ++k) {
    __syncthreads();  // previous tile's readers done before overwrite
#pragma unroll
    for (int i = 0; i < (S * TILE) / THREADS; ++i) {  // 4 entries/thread
      int idx = t + THREADS * i;
      int s = idx >> 6;         // idx / TILE
      int jj = idx & (TILE - 1);
      int n = tbase + s * sliceLen + k * TILE + jj;
      float qx = ref[n * 3 + 0], qy = ref[n * 3 + 1], qz = ref[n * 3 + 2];
      lds[s * LSTRIDE + jj] =
          (float4_t){qx, qy, qz, qx * qx + qy * qy + qz * qz};
    }
    __syncthreads();
    const float4_t* tp = lds + g * LSTRIDE;  // uniform per 16-lane group
    // Software pipeline: q for step j held in regs while step j+1 loads.
    float4_t qc0 = tp[0], qc1 = tp[1], qc2 = tp[2], qc3 = tp[3];
#pragma unroll
    for (int j = 0; j < TILE; j += 4) {
      float4_t qn0, qn1, qn2, qn3;
      if (j + 4 < TILE) {  // compile-time under full unroll
        qn0 = tp[j + 4]; qn1 = tp[j + 5]; qn2 = tp[j + 6]; qn3 = tp[j + 7];
      }
      float2_t q0xy = __builtin_shufflevector(qc0, qc0, 0, 1);
      float2_t q0zw = __builtin_shufflevector(qc0, qc0, 2, 3);
      float2_t q1xy = __builtin_shufflevector(qc1, qc1, 0, 1);
      float2_t q1zw = __builtin_shufflevector(qc1, qc1, 2, 3);
      float2_t q2xy = __builtin_shufflevector(qc2, qc2, 0, 1);
      float2_t q2zw = __builtin_shufflevector(qc2, qc2, 2, 3);
      float2_t q3xy = __builtin_shufflevector(qc3, qc3, 0, 1);
      float2_t q3zw = __builtin_shufflevector(qc3, qc3, 2, 3);
#pragma unroll
      for (int i = 0; i < P / 2; ++i) {
        // d = ax*qx + ay*qy + az*qz + qw, two points per packed chain
        float2_t d0 = pk_fma_bl(a2x[i], q0xy,
                        pk_fma_bh(a2y[i], q0xy, pk_fma_bl_bh(a2z[i], q0zw)));
        float2_t d1 = pk_fma_bl(a2x[i], q1xy,
                        pk_fma_bh(a2y[i], q1xy, pk_fma_bl_bh(a2z[i], q1zw)));
        float2_t d2 = pk_fma_bl(a2x[i], q2xy,
                        pk_fma_bh(a2y[i], q2xy, pk_fma_bl_bh(a2z[i], q2zw)));
        float2_t d3 = pk_fma_bl(a2x[i], q3xy,
                        pk_fma_bh(a2y[i], q3xy, pk_fma_bl_bh(a2z[i], q3zw)));
        mlo[i] = fminf(fminf(mlo[i], d0.x), d1.x);  // v_min3
        mlo[i] = fminf(fminf(mlo[i], d2.x), d3.x);
        mhi[i] = fminf(fminf(mhi[i], d0.y), d1.y);
        mhi[i] = fminf(fminf(mhi[i], d2.y), d3.y);
      }
      if (j + 4 < TILE) { qc0 = qn0; qc1 = qn1; qc2 = qn2; qc3 = qn3; }
    }
  }

  // Combine the S slice-mins per point, add |p|^2 back, store per-split min.
  __syncthreads();
  float* lmin = (float*)lds;  // [S][G] floats (16 KB, overlays staging)
#pragma unroll
  for (int i = 0; i < P / 2; ++i) {
    lmin[g * G + (l + 16 * (2 * i))] = mlo[i];
    lmin[g * G + (l + 16 * (2 * i + 1))] = mhi[i];
  }
  __syncthreads();
  if (t < G) {
    float mn = 3.0e38f;
#pragma unroll
    for (int s = 0; s < S; ++s) mn = fminf(mn, lmin[s * G + t]);
    int p = pbase + t;
    float x = src[p * 3 + 0], y = src[p * 3 + 1], z = src[p * 3 + 2];
    int pid = (b * 2 + dir) * M + p;               // global point id
    wsmin[(size_t)pid * TSPLIT + ts] = (x * x + y * y + z * z) + mn;
  }
}

// Min over the TSPLIT partials per point, then sum everything (double acc).
__global__ __launch_bounds__(256) void chamfer_reduce_kernel(
    const float* __restrict__ wsmin, float* __restrict__ out, int npts,
    float scale) {
  int tid = blockIdx.x * blockDim.x + threadIdx.x;
  int stride = gridDim.x * blockDim.x;
  double acc = 0.0;
  for (int p = tid; p < npts; p += stride) {
    float2_t v = ((const float2_t*)wsmin)[p];  // TSPLIT=2 contiguous
    acc += (double)fminf(v.x, v.y);
  }
  for (int off = 32; off > 0; off >>= 1) acc += __shfl_down(acc, off, 64);
  __shared__ double wsum[256 / 64];
  int t = threadIdx.x;
  if ((t & 63) == 0) wsum[t >> 6] = acc;
  __syncthreads();
  if (t == 0) {
    double s = 0.0;
#pragma unroll
    for (int w = 0; w < 256 / 64; ++w) s += wsum[w];
    atomicAdd(out, (float)(s * (double)scale));
  }
}

extern "C" void kernel_launch(void* const* d_in, const int* in_sizes, int n_in,
                              void* d_out, int out_size, void* d_ws,
                              size_t ws_size, hipStream_t stream) {
  const float* pred = (const float*)d_in[0];
  const float* target = (const float*)d_in[1];
  float* out = (float*)d_out;
  float* wsmin = (float*)d_ws;  // B*2*M*TSPLIT floats = 512 KB
  const int B = 4;
  const int M = in_sizes[0] / (B * 3);  // 8192

  // mean_b[ mean_m(min) + mean_n(min) ] with M==N  ->  sum_all / (B*M)
  float scale = 1.0f / (float)(B * M);

  hipMemsetAsync(out, 0, sizeof(float), stream);  // d_out is poisoned 0xAA
  int blocks = B * 2 * (M / G) * TSPLIT;          // 1024
  chamfer_min_kernel<<<blocks, THREADS, 0, stream>>>(pred, target, wsmin, M);
  int npts = B * 2 * M;                           // 65536
  chamfer_reduce_kernel<<<64, 256, 0, stream>>>(wsmin, out, npts, scale);
}